// Round 8
// baseline (718.614 us; speedup 1.0000x reference)
//
#include <hip/hip_runtime.h>

#define BB  256
#define TT  500
#define ENC 700
#define ENC_PAD 704   // rows 700..703 of w1t are zeros (gather padding target)
#define HID 128
#define LMAX 80       // per-row index-list capacity; mean n=35, sd 4.1

// ---------------------------------------------------------------------------
// Kernel 1: transpose w1 (HID, ENC) -> w1t (ENC_PAD, HID); pad rows = 0
// ---------------------------------------------------------------------------
__global__ __launch_bounds__(128) void transpose_w1_kernel(const float* __restrict__ w1,
                                                           float* __restrict__ w1t) {
    int c = blockIdx.x;      // 0..ENC_PAD-1
    int h = threadIdx.x;     // 0..HID-1
    w1t[c * HID + h] = (c < ENC) ? w1[h * ENC + c] : 0.0f;
}

// ---------------------------------------------------------------------------
// Fused kernel: one block per batch element b. 256 threads (4 waves).
// Per 50-step chunk:
//   Phase A: all 4 waves compress+gather h rows (pairs of rows per wave,
//            32 global loads in flight; w1t is L2-resident) -> h in LDS only.
//   Phase B: proven scan / o_t reduce / layer-2 (verbatim from R3-R6
//            validated kernels).
// Exactness: per-row per-channel single-chain adds in strictly ascending
// column order; zero-column (700) padding; fp32 formulas unchanged.
// ---------------------------------------------------------------------------

__device__ __forceinline__ void load_xrow(const float* __restrict__ xrow,
                                          float* xv, int lane) {
    #pragma unroll
    for (int k = 0; k < 11; ++k) {
        int c = k * 64 + lane;
        xv[k] = (c < ENC) ? xrow[c] : 0.0f;
    }
}

// ballot-compress one row into a wave-local ascending list; returns npad (x16)
__device__ __forceinline__ int compress_row(const float* xv, ushort* list, int lane,
                                            unsigned long long lt) {
    int base = 0;
    #pragma unroll
    for (int k = 0; k < 11; ++k) {
        bool act = (xv[k] != 0.0f);
        unsigned long long m = __ballot(act);
        if (act) {
            int pos = base + (int)__popcll(m & lt);
            if (pos < LMAX) list[pos] = (ushort)(k * 64 + lane);
        }
        base += (int)__popcll(m);
    }
    int n = (base < LMAX) ? base : LMAX;
    int npad = (n + 15) & ~15;            // <= LMAX since n <= LMAX
    for (int p = n + lane; p < npad; p += 64) list[p] = (ushort)ENC;
    return npad;
}

// load 8 w1t column-pairs (packed as 4x2 ushort in iv) and accumulate in
// strictly ascending list order (ordered adds — do not reassociate)
__device__ __forceinline__ void gather8(const float* __restrict__ wb, uint4 iv,
                                        float& ax, float& ay) {
    float2 v0 = *(const float2*)(wb + ((size_t)(iv.x & 0xffffu) << 7));
    float2 v1 = *(const float2*)(wb + ((size_t)(iv.x >> 16)     << 7));
    float2 v2 = *(const float2*)(wb + ((size_t)(iv.y & 0xffffu) << 7));
    float2 v3 = *(const float2*)(wb + ((size_t)(iv.y >> 16)     << 7));
    float2 v4 = *(const float2*)(wb + ((size_t)(iv.z & 0xffffu) << 7));
    float2 v5 = *(const float2*)(wb + ((size_t)(iv.z >> 16)     << 7));
    float2 v6 = *(const float2*)(wb + ((size_t)(iv.w & 0xffffu) << 7));
    float2 v7 = *(const float2*)(wb + ((size_t)(iv.w >> 16)     << 7));
    ax += v0.x; ay += v0.y;
    ax += v1.x; ay += v1.y;
    ax += v2.x; ay += v2.y;
    ax += v3.x; ay += v3.y;
    ax += v4.x; ay += v4.y;
    ax += v5.x; ay += v5.y;
    ax += v6.x; ay += v6.y;
    ax += v7.x; ay += v7.y;
}

__global__ __launch_bounds__(256, 1) void fused_kernel(const float* __restrict__ x,
                                                       const float* __restrict__ w1t,
                                                       const float* __restrict__ w2,
                                                       float* __restrict__ out) {
    __shared__ float hch[50 * 132];                 // 26.4 KB: h chunk, LDS-only
    __shared__ float vbuf[50 * 129];                // 25.8 KB
    __shared__ float pbuf[2][50];
    __shared__ __align__(16) ushort lists[4][2][LMAX];   // 1.28 KB, wave-local

    const int b = blockIdx.x;
    const int tid = threadIdx.x;
    const int lane = tid & 63;
    const int w = tid >> 6;
    const unsigned long long lt = (1ull << lane) - 1ull;

    const float D   = 0.95122942450071400910f;                                 // exp(-1/20)
    const float CD  = (float)(0.13591409142295226 * 0.95122942450071400910);   // (e/20)*d
    const float CRD = (float)(-0.27182818284590452 * 0.95122942450071400910);  // (-2e/20)*d

    float ap = 0.f, aq = 0.f, rp = 0.f, rq = 0.f;   // layer-1 state (ch = tid < 128)
    float Ap = 0.f, Aq = 0.f, Rp = 0.f, Rq = 0.f;   // layer-2 state (redundant)
    const float w2v = (tid < HID) ? w2[tid] : 0.0f;

    const float* wb = w1t + 2 * lane;               // channel pair base (2lane, 2lane+1)
    ushort* l0 = lists[w][0];
    ushort* l1 = lists[w][1];

    for (int chunk = 0; chunk < 10; ++chunk) {
        // ================= Phase A: gather 50 rows of h into LDS ==========
        {
            const float* xbase = x + ((size_t)b * TT + chunk * 50) * ENC;
            float xa[11], xb[11], xa2[11], xb2[11];
            int p = w;                              // pair index: rows 2p, 2p+1
            if (p < 25) {
                load_xrow(xbase + (size_t)(2 * p) * ENC, xa, lane);
                load_xrow(xbase + (size_t)(2 * p + 1) * ENC, xb, lane);
            }
            for (; p < 25; p += 4) {
                int npad0 = compress_row(xa, l0, lane, lt);
                int npad1 = compress_row(xb, l1, lane, lt);
                int jmax = (npad0 > npad1) ? npad0 : npad1;
                for (int q2 = npad0 + lane; q2 < jmax; q2 += 64) l0[q2] = (ushort)ENC;
                for (int q2 = npad1 + lane; q2 < jmax; q2 += 64) l1[q2] = (ushort)ENC;

                if (p + 4 < 25) {                   // prefetch next pair's x rows
                    load_xrow(xbase + (size_t)(2 * (p + 4)) * ENC, xa2, lane);
                    load_xrow(xbase + (size_t)(2 * (p + 4) + 1) * ENC, xb2, lane);
                }

                float a0x = 0.f, a0y = 0.f, a1x = 0.f, a1y = 0.f;
                for (int j = 0; j < jmax; j += 16) {
                    uint4 ia0 = *(const uint4*)&l0[j];
                    uint4 ia1 = *(const uint4*)&l0[j + 8];
                    uint4 ib0 = *(const uint4*)&l1[j];
                    uint4 ib1 = *(const uint4*)&l1[j + 8];
                    gather8(wb, ia0, a0x, a0y);
                    gather8(wb, ia1, a0x, a0y);
                    gather8(wb, ib0, a1x, a1y);
                    gather8(wb, ib1, a1x, a1y);
                }
                *(float2*)&hch[(2 * p) * 132 + 2 * lane]     = make_float2(a0x, a0y);
                *(float2*)&hch[(2 * p + 1) * 132 + 2 * lane] = make_float2(a1x, a1y);

                if (p + 4 < 25) {
                    #pragma unroll
                    for (int k = 0; k < 11; ++k) { xa[k] = xa2[k]; xb[k] = xb2[k]; }
                }
            }
        }
        __syncthreads();                            // hch complete

        // ================= Phase B: proven scan / reduce / layer-2 ========
        if (tid < HID) {
            #pragma unroll
            for (int tl = 0; tl < 50; ++tl) {
                float hv = hch[tl * 132 + tid];
                float y = fmaf(D, aq, CD * ap);
                aq = y;
                ap = fmaf(D, ap, hv);
                float q = fmaf(D, rq, CRD * rp);
                float u = y + q;
                float s = (u >= 1.0f) ? 1.0f : 0.0f;
                rq = q;
                rp = fmaf(D, rp, s);
                vbuf[tl * 129 + tid] = s * w2v;
            }
        }
        __syncthreads();                            // vbuf ready; hch free

        if (tid < 50) {
            const float* row = &vbuf[tid * 129];
            float a0 = 0.f, a1 = 0.f, a2 = 0.f, a3 = 0.f;
            #pragma unroll
            for (int kk = 0; kk < 64; kk += 4) {
                a0 += row[kk]; a1 += row[kk + 1]; a2 += row[kk + 2]; a3 += row[kk + 3];
            }
            pbuf[0][tid] = (a0 + a1) + (a2 + a3);
        } else if (tid >= 64 && tid < 114) {
            const float* row = &vbuf[(tid - 64) * 129 + 64];
            float a0 = 0.f, a1 = 0.f, a2 = 0.f, a3 = 0.f;
            #pragma unroll
            for (int kk = 0; kk < 64; kk += 4) {
                a0 += row[kk]; a1 += row[kk + 1]; a2 += row[kk + 2]; a3 += row[kk + 3];
            }
            pbuf[1][tid - 64] = (a0 + a1) + (a2 + a3);
        }
        __syncthreads();                            // pbuf ready

        float my_s2 = 0.f;
        #pragma unroll
        for (int tl = 0; tl < 50; ++tl) {
            float ot = pbuf[0][tl] + pbuf[1][tl];
            float y2 = fmaf(D, Aq, CD * Ap);
            Aq = y2;
            Ap = fmaf(D, Ap, ot);
            float q2 = fmaf(D, Rq, CRD * Rp);
            float u2 = y2 + q2;
            float s2 = (u2 >= 1.0f) ? 1.0f : 0.0f;
            Rq = q2;
            Rp = fmaf(D, Rp, s2);
            if (tl == tid) my_s2 = s2;
        }
        if (tid < 50) out[(size_t)b * TT + chunk * 50 + tid] = my_s2;
        // next chunk's phase-A hch writes are safe: every thread writes hch
        // only after its own layer-2 (program order), and phase-B reads of
        // hch ended before the post-scan barrier above; vbuf/pbuf overwrite
        // is fenced by next chunk's barriers.
    }
}

// ---------------------------------------------------------------------------
extern "C" void kernel_launch(void* const* d_in, const int* in_sizes, int n_in,
                              void* d_out, int out_size, void* d_ws, size_t ws_size,
                              hipStream_t stream) {
    const float* x  = (const float*)d_in[0];   // (B, T, ENC) binary fp32
    const float* w1 = (const float*)d_in[1];   // (HID, ENC)
    const float* w2 = (const float*)d_in[2];   // (1, HID)
    float* out = (float*)d_out;                // (B, T, 1)

    float* w1t = (float*)d_ws;                 // (ENC_PAD, HID) = 360 KB only

    hipLaunchKernelGGL(transpose_w1_kernel, dim3(ENC_PAD), dim3(HID), 0, stream,
                       w1, w1t);
    hipLaunchKernelGGL(fused_kernel, dim3(BB), dim3(256), 0, stream,
                       x, w1t, w2, out);
}